// Round 6
// baseline (129.299 us; speedup 1.0000x reference)
//
#include <hip/hip_runtime.h>
#include <hip/hip_bf16.h>
#include <stdint.h>

typedef __attribute__((ext_vector_type(8))) short bf16x8;
typedef __attribute__((ext_vector_type(4))) float f32x4;
typedef __attribute__((ext_vector_type(16))) float f32x16;

#define S_LEN 2048
#define D_DIM 128
#define HQ_N  32
#define KVB   32            // kv rows per step-tile
#define KTILE_B 8192        // 32 rows x 256B (bf16 row of 128)
#define VTILE_B 8192        // 128 d x 64B (bf16 row of 32 kv)

__device__ __forceinline__ ushort f2bf(float f) {
  union { float f; uint32_t u; } c; c.f = f;
  uint32_t u = c.u;
  u += 0x7FFFu + ((u >> 16) & 1u);   // round-nearest-even
  return (ushort)(u >> 16);
}

__device__ __forceinline__ uint32_t cvtpk(float lo, float hi) {
  uint32_t r;
  asm("v_cvt_pk_bf16_f32 %0, %1, %2" : "=v"(r) : "v"(lo), "v"(hi));
  return r;
}

__device__ __forceinline__ void gload16(const void* g, void* l) {
  __builtin_amdgcn_global_load_lds(
      (const __attribute__((address_space(1))) uint32_t*)g,
      (__attribute__((address_space(3))) uint32_t*)l, 16, 0, 0);
}

// ---- prepass: K fp32 row-major -> bf16, chunk-swizzled; 32-row subtiles are
// contiguous 8KB halves of the 64-row tile. Element (r,d):
//   byte = r*256 + ((d>>3)^(r&15))*16 + (d&7)*2
__global__ __launch_bounds__(256) void prep_k(const float* __restrict__ K,
                                              ushort* __restrict__ KT) {
  int tid  = blockIdx.x * 256 + threadIdx.x;   // 262144
  int tile = tid >> 10;
  int off  = tid & 1023;
  int r    = off >> 4;
  int gp   = off & 15;
  int g    = gp ^ (r & 15);
  const float* src = K + ((size_t)(tile * 64 + r)) * D_DIM + (g << 3);
  float4 x = *(const float4*)src;
  float4 y = *(const float4*)(src + 4);
  union { ushort u[8]; bf16x8 v; } o;
  o.u[0] = f2bf(x.x); o.u[1] = f2bf(x.y); o.u[2] = f2bf(x.z); o.u[3] = f2bf(x.w);
  o.u[4] = f2bf(y.x); o.u[5] = f2bf(y.y); o.u[6] = f2bf(y.z); o.u[7] = f2bf(y.w);
  *(bf16x8*)(KT + (size_t)tid * 8) = o.v;
}

// ---- prepass: V fp32 -> bf16 TRANSPOSED 32-kv tiles [d=128][kv=32], swizzled:
// tile = head*64 + kt. Element (d,kv): byte = d*64 + ((kv>>3)^(d&3))*16 + (kv&7)*2
__global__ __launch_bounds__(256) void prep_v(const float* __restrict__ V,
                                              ushort* __restrict__ VT) {
  int tid  = blockIdx.x * 256 + threadIdx.x;   // 262144
  int tile = tid >> 9;         // 512 chunks per 8KB tile
  int off  = tid & 511;
  int d    = off >> 2;
  int gp   = off & 3;
  int g    = gp ^ (d & 3);
  int kv0  = (tile & 63) * KVB + (g << 3);
  const float* src = V + ((size_t)(tile >> 6) * S_LEN + kv0) * D_DIM + d;
  union { ushort u[8]; bf16x8 v; } o;
  #pragma unroll
  for (int j = 0; j < 8; ++j) o.u[j] = f2bf(src[(size_t)j * D_DIM]);
  *(bf16x8*)(VT + (size_t)tid * 8) = o.v;
}

// ---- flash attention: 2-wave blocks, KVB=32, backfill-balanced ----
__global__ __launch_bounds__(128, 2) void attn_fwd(
    const float* __restrict__ Q, const ushort* __restrict__ KT,
    const ushort* __restrict__ VT, float* __restrict__ O) {
  const int j    = 31 - blockIdx.x;      // longest blocks dispatched first
  const int h    = blockIdx.y;
  const int hkv  = h >> 2;
  const int tid  = threadIdx.x;          // 0..127
  const int w    = tid >> 6;             // wave 0..1
  const int lane = tid & 63;
  const int l31  = lane & 31;
  const int hi   = lane >> 5;
  const int qw   = j * 64 + w * 32;      // wave's first q row
  const int qrow = qw + l31;             // lane's q row

  __shared__ ushort K_lds[2][KTILE_B / 2];
  __shared__ ushort V_lds[2][VTILE_B / 2];

  const char* ktiles = (const char*)KT + (size_t)hkv * 64 * KTILE_B;
  const char* vtiles = (const char*)VT + (size_t)hkv * 64 * VTILE_B;
  const int nsteps = 2 * j + 2;

  // prologue: stage tile 0
  #pragma unroll
  for (int i = 0; i < 4; ++i) {
    int off = i * 2048 + tid * 16;
    gload16(ktiles + off, (char*)K_lds[0] + off);
    gload16(vtiles + off, (char*)V_lds[0] + off);
  }

  // Q fragments (B operand), log2-domain scale
  const float scale = 0.08838834764831845f * 1.4426950408889634f;
  bf16x8 qf[8];
  {
    const float* qp = Q + ((size_t)h * S_LEN + qrow) * D_DIM;
    #pragma unroll
    for (int s = 0; s < 8; ++s) {
      const float* p = qp + 16 * s + 8 * hi;
      float4 x = *(const float4*)p;
      float4 y = *(const float4*)(p + 4);
      bf16x8 f;
      f[0] = (short)f2bf(x.x * scale); f[1] = (short)f2bf(x.y * scale);
      f[2] = (short)f2bf(x.z * scale); f[3] = (short)f2bf(x.w * scale);
      f[4] = (short)f2bf(y.x * scale); f[5] = (short)f2bf(y.y * scale);
      f[6] = (short)f2bf(y.z * scale); f[7] = (short)f2bf(y.w * scale);
      qf[s] = f;
    }
  }

  f32x16 o[4] = {};        // O^T: q=l31, d = 32*dt + (r&3)+8*(r>>2)+4*hi
  float mrow = -1e30f, lsum = 0.f;

  __syncthreads();

  for (int kt = 0; kt < nsteps; ++kt) {
    const int cur = kt & 1;
    if (kt + 1 < nsteps) {
      const char* gk = ktiles + (size_t)(kt + 1) * KTILE_B;
      const char* gv = vtiles + (size_t)(kt + 1) * VTILE_B;
      #pragma unroll
      for (int i = 0; i < 4; ++i) {
        int off = i * 2048 + tid * 16;
        gload16(gk + off, (char*)K_lds[cur ^ 1] + off);
        gload16(gv + off, (char*)V_lds[cur ^ 1] + off);
      }
    }

    if (KVB * kt <= qw + 31) {           // wave-uniform causal skip
      const char* Kl = (const char*)K_lds[cur];
      const char* Vl = (const char*)V_lds[cur];

      // ---- S^T = K Q ----
      f32x16 st = {};
      __builtin_amdgcn_s_setprio(1);
      #pragma unroll
      for (int s = 0; s < 8; ++s) {
        int gp = ((s << 1) + hi) ^ (l31 & 15);
        bf16x8 kf = *(const bf16x8*)(Kl + l31 * 256 + gp * 16);
        st = __builtin_amdgcn_mfma_f32_32x32x16_bf16(kf, qf[s], st, 0, 0, 0);
      }
      __builtin_amdgcn_s_setprio(0);

      // ---- causal mask (diag tiles only) ----
      if (KVB * kt + 31 > qw) {
        #pragma unroll
        for (int r = 0; r < 16; ++r) {
          int kv = KVB * kt + (r & 3) + 8 * (r >> 2) + 4 * hi;
          if (kv > qrow) st[r] = -1e30f;
        }
      }

      // ---- online softmax, lane-local rows; cross-half via shfl (validated) ----
      float t8[8];
      #pragma unroll
      for (int e = 0; e < 8; ++e) t8[e] = fmaxf(st[e], st[e + 8]);
      float mx = fmaxf(fmaxf(fmaxf(t8[0], t8[1]), fmaxf(t8[2], t8[3])),
                       fmaxf(fmaxf(t8[4], t8[5]), fmaxf(t8[6], t8[7])));
      mx = fmaxf(mx, __shfl_xor(mx, 32));
      float mnew = fmaxf(mrow, mx);
      float alpha = exp2f(mrow - mnew);
      mrow = mnew;

      #pragma unroll
      for (int e = 0; e < 16; ++e) st[e] = exp2f(st[e] - mnew);
      float s8[8];
      #pragma unroll
      for (int e = 0; e < 8; ++e) s8[e] = st[e] + st[e + 8];
      float rsum = ((s8[0] + s8[1]) + (s8[2] + s8[3])) +
                   ((s8[4] + s8[5]) + (s8[6] + s8[7]));
      rsum += __shfl_xor(rsum, 32);
      lsum = lsum * alpha + rsum;

      #pragma unroll
      for (int dt = 0; dt < 4; ++dt) o[dt] *= alpha;

      // ---- pack P^T: cvt_pk + permlane32_swap (R4-validated recipe) ----
      bf16x8 pb[2];
      #pragma unroll
      for (int c = 0; c < 2; ++c) {
        const int r0 = c * 8;
        uint32_t a0 = cvtpk(st[r0 + 0], st[r0 + 1]);
        uint32_t b0 = cvtpk(st[r0 + 4], st[r0 + 5]);
        asm volatile("v_permlane32_swap_b32 %0, %1" : "+v"(a0), "+v"(b0));
        uint32_t a1 = cvtpk(st[r0 + 2], st[r0 + 3]);
        uint32_t b1 = cvtpk(st[r0 + 6], st[r0 + 7]);
        asm volatile("v_permlane32_swap_b32 %0, %1" : "+v"(a1), "+v"(b1));
        union { uint32_t u[4]; bf16x8 v; } pu;
        pu.u[0] = a0; pu.u[1] = a1; pu.u[2] = b0; pu.u[3] = b1;
        pb[c] = pu.v;
      }

      // ---- O^T += V^T P^T ----
      __builtin_amdgcn_s_setprio(1);
      #pragma unroll
      for (int dt = 0; dt < 4; ++dt) {
        const char* vrow = Vl + (32 * dt + l31) * 64;
        #pragma unroll
        for (int c = 0; c < 2; ++c) {
          int gp = ((c << 1) + hi) ^ (l31 & 3);
          bf16x8 vf = *(const bf16x8*)(vrow + gp * 16);
          o[dt] = __builtin_amdgcn_mfma_f32_32x32x16_bf16(vf, pb[c], o[dt], 0, 0, 0);
        }
      }
      __builtin_amdgcn_s_setprio(0);
    }
    __syncthreads();
  }

  // ---- epilogue ----
  const float inv = 1.0f / lsum;
  float* op = O + ((size_t)h * S_LEN + qrow) * D_DIM;
  #pragma unroll
  for (int dt = 0; dt < 4; ++dt)
    #pragma unroll
    for (int rq = 0; rq < 4; ++rq) {
      f32x4 vv;
      #pragma unroll
      for (int jj = 0; jj < 4; ++jj) vv[jj] = o[dt][rq * 4 + jj] * inv;
      *(f32x4*)(op + 32 * dt + 8 * rq + 4 * hi) = vv;
    }
}

extern "C" void kernel_launch(void* const* d_in, const int* in_sizes, int n_in,
                              void* d_out, int out_size, void* d_ws, size_t ws_size,
                              hipStream_t stream) {
  const float* Q = (const float*)d_in[0];
  const float* K = (const float*)d_in[1];
  const float* V = (const float*)d_in[2];
  float* O = (float*)d_out;
  ushort* wsK = (ushort*)d_ws;
  ushort* wsV = wsK + (size_t)8 * 64 * (KTILE_B / 2);   // +4MB
  prep_k<<<1024, 256, 0, stream>>>(K, wsK);
  prep_v<<<1024, 256, 0, stream>>>(V, wsV);
  attn_fwd<<<dim3(32, HQ_N), 128, 0, stream>>>(Q, wsK, wsV, O);
}

// Round 7
// 83.607 us; speedup vs baseline: 1.5465x; 1.5465x over previous
//
#include <hip/hip_runtime.h>
#include <hip/hip_bf16.h>
#include <stdint.h>

typedef __attribute__((ext_vector_type(8))) short bf16x8;
typedef __attribute__((ext_vector_type(4))) float f32x4;
typedef __attribute__((ext_vector_type(16))) float f32x16;

#define S_LEN 2048
#define D_DIM 128
#define HQ_N  32
#define KVB   32
#define NT    64            // 32-row kv tiles per kv-head
#define KTILE_B 8192        // one tile: 512 chunks x 16B, fragment-ordered
#define VTILE_B 8192

__device__ __forceinline__ ushort f2bf(float f) {
  union { float f; uint32_t u; } c; c.f = f;
  uint32_t u = c.u;
  u += 0x7FFFu + ((u >> 16) & 1u);   // round-nearest-even
  return (ushort)(u >> 16);
}

__device__ __forceinline__ uint32_t cvtpk(float lo, float hi) {
  uint32_t r;
  asm("v_cvt_pk_bf16_f32 %0, %1, %2" : "=v"(r) : "v"(lo), "v"(hi));
  return r;
}

// ---- prep K: fragment-ordered bf16 tiles ----
// tile = hkv*64 + kt. chunk c = s*64 + lane (lane = hi*32 + l31):
//   content = K[tile*32 + l31][16s + 8hi .. +7]
__global__ __launch_bounds__(256) void prep_k(const float* __restrict__ K,
                                              ushort* __restrict__ KT) {
  int tid  = blockIdx.x * 256 + threadIdx.x;   // 262144
  int tile = tid >> 9;
  int c    = tid & 511;
  int s    = c >> 6;
  int lane = c & 63;
  int l31  = lane & 31, hi = lane >> 5;
  const float* src = K + ((size_t)(tile * 32 + l31)) * D_DIM + 16 * s + 8 * hi;
  float4 x = *(const float4*)src;
  float4 y = *(const float4*)(src + 4);
  union { ushort u[8]; bf16x8 v; } o;
  o.u[0] = f2bf(x.x); o.u[1] = f2bf(x.y); o.u[2] = f2bf(x.z); o.u[3] = f2bf(x.w);
  o.u[4] = f2bf(y.x); o.u[5] = f2bf(y.y); o.u[6] = f2bf(y.z); o.u[7] = f2bf(y.w);
  *(bf16x8*)(KT + (size_t)tid * 8) = o.v;
}

// ---- prep V: fragment-ordered transposed bf16 tiles ----
// tile = hkv*64 + kt. chunk cc = dt*128 + c*64 + hi*32 + l31:
//   content = V^T[32dt + l31][kt*32 + 16c + 8hi .. +7]  (gathered stride-D)
__global__ __launch_bounds__(256) void prep_v(const float* __restrict__ V,
                                              ushort* __restrict__ VT) {
  int tid  = blockIdx.x * 256 + threadIdx.x;   // 262144
  int tile = tid >> 9;
  int cc   = tid & 511;
  int l31  = cc & 31;
  int hi   = (cc >> 5) & 1;
  int c    = (cc >> 6) & 1;
  int dt   = cc >> 7;
  int hkv  = tile >> 6, kt = tile & 63;
  const float* src = V + ((size_t)hkv * S_LEN + kt * 32 + 16 * c + 8 * hi) * D_DIM
                       + 32 * dt + l31;
  union { ushort u[8]; bf16x8 v; } o;
  #pragma unroll
  for (int jj = 0; jj < 8; ++jj) o.u[jj] = f2bf(src[(size_t)jj * D_DIM]);
  *(bf16x8*)(VT + (size_t)tid * 8) = o.v;
}

// ---- flash attention: 1-wave blocks, no LDS, no barriers, L2-direct KV ----
__global__ __launch_bounds__(64, 2) void attn_fwd(
    const float* __restrict__ Q, const ushort* __restrict__ KT,
    const ushort* __restrict__ VT, float* __restrict__ O) {
  const int id   = blockIdx.x;           // 2048 blocks
  const int g    = id & 7;               // kv-head -> XCD affinity (id%8 round-robin)
  const int rest = id >> 3;
  const int qh   = rest & 3;
  const int j    = 63 - (rest >> 2);     // longest first within each XCD
  const int h    = g * 4 + qh;
  const int lane = threadIdx.x;
  const int l31  = lane & 31;
  const int hi   = lane >> 5;
  const int qrow = j * 32 + l31;

  const char* kt_base = (const char*)KT + (size_t)g * NT * KTILE_B;
  const char* vt_base = (const char*)VT + (size_t)g * NT * VTILE_B;

  // Q fragments (B operand), log2-domain scale
  const float scale = 0.08838834764831845f * 1.4426950408889634f;
  bf16x8 qf[8];
  {
    const float* qp = Q + ((size_t)h * S_LEN + qrow) * D_DIM;
    #pragma unroll
    for (int s = 0; s < 8; ++s) {
      const float* p = qp + 16 * s + 8 * hi;
      float4 x = *(const float4*)p;
      float4 y = *(const float4*)(p + 4);
      bf16x8 f;
      f[0] = (short)f2bf(x.x * scale); f[1] = (short)f2bf(x.y * scale);
      f[2] = (short)f2bf(x.z * scale); f[3] = (short)f2bf(x.w * scale);
      f[4] = (short)f2bf(y.x * scale); f[5] = (short)f2bf(y.y * scale);
      f[6] = (short)f2bf(y.z * scale); f[7] = (short)f2bf(y.w * scale);
      qf[s] = f;
    }
  }

  f32x16 o4[4] = {};       // O^T: q=l31, d = 32*dt + (r&3)+8*(r>>2)+4*hi
  float mrow = -1e30f, lsum = 0.f;

  for (int kt = 0; kt <= j; ++kt) {
    const char* kp = kt_base + (size_t)kt * KTILE_B;
    const char* vp = vt_base + (size_t)kt * VTILE_B;

    // issue ALL 16 fragment loads up front; V latency hides under QK+softmax
    bf16x8 kf[8], vf[8];
    #pragma unroll
    for (int s = 0; s < 8; ++s)
      kf[s] = *(const bf16x8*)(kp + (s * 64 + lane) * 16);
    #pragma unroll
    for (int u = 0; u < 8; ++u)
      vf[u] = *(const bf16x8*)(vp + (u * 64 + lane) * 16);

    // ---- S^T = K Q ----
    f32x16 st = {};
    __builtin_amdgcn_s_setprio(1);
    #pragma unroll
    for (int s = 0; s < 8; ++s)
      st = __builtin_amdgcn_mfma_f32_32x32x16_bf16(kf[s], qf[s], st, 0, 0, 0);
    __builtin_amdgcn_s_setprio(0);

    // ---- causal mask (diagonal tile only) ----
    if (kt == j) {
      #pragma unroll
      for (int r = 0; r < 16; ++r) {
        int kv = KVB * kt + (r & 3) + 8 * (r >> 2) + 4 * hi;
        if (kv > qrow) st[r] = -1e30f;
      }
    }

    // ---- online softmax, lane-local rows; cross-half via shfl ----
    float t8[8];
    #pragma unroll
    for (int e = 0; e < 8; ++e) t8[e] = fmaxf(st[e], st[e + 8]);
    float mx = fmaxf(fmaxf(fmaxf(t8[0], t8[1]), fmaxf(t8[2], t8[3])),
                     fmaxf(fmaxf(t8[4], t8[5]), fmaxf(t8[6], t8[7])));
    mx = fmaxf(mx, __shfl_xor(mx, 32));
    float mnew = fmaxf(mrow, mx);
    float alpha = exp2f(mrow - mnew);
    mrow = mnew;

    #pragma unroll
    for (int e = 0; e < 16; ++e) st[e] = exp2f(st[e] - mnew);
    float s8[8];
    #pragma unroll
    for (int e = 0; e < 8; ++e) s8[e] = st[e] + st[e + 8];
    float rsum = ((s8[0] + s8[1]) + (s8[2] + s8[3])) +
                 ((s8[4] + s8[5]) + (s8[6] + s8[7]));
    rsum += __shfl_xor(rsum, 32);
    lsum = lsum * alpha + rsum;

    #pragma unroll
    for (int dt = 0; dt < 4; ++dt) o4[dt] *= alpha;

    // ---- pack P^T: cvt_pk + permlane32_swap (validated recipe) ----
    bf16x8 pb[2];
    #pragma unroll
    for (int c = 0; c < 2; ++c) {
      const int r0 = c * 8;
      uint32_t a0 = cvtpk(st[r0 + 0], st[r0 + 1]);
      uint32_t b0 = cvtpk(st[r0 + 4], st[r0 + 5]);
      asm volatile("v_permlane32_swap_b32 %0, %1" : "+v"(a0), "+v"(b0));
      uint32_t a1 = cvtpk(st[r0 + 2], st[r0 + 3]);
      uint32_t b1 = cvtpk(st[r0 + 6], st[r0 + 7]);
      asm volatile("v_permlane32_swap_b32 %0, %1" : "+v"(a1), "+v"(b1));
      union { uint32_t u[4]; bf16x8 v; } pu;
      pu.u[0] = a0; pu.u[1] = a1; pu.u[2] = b0; pu.u[3] = b1;
      pb[c] = pu.v;
    }

    // ---- O^T += V^T P^T ----
    __builtin_amdgcn_s_setprio(1);
    #pragma unroll
    for (int dt = 0; dt < 4; ++dt) {
      o4[dt] = __builtin_amdgcn_mfma_f32_32x32x16_bf16(vf[2 * dt + 0], pb[0], o4[dt], 0, 0, 0);
      o4[dt] = __builtin_amdgcn_mfma_f32_32x32x16_bf16(vf[2 * dt + 1], pb[1], o4[dt], 0, 0, 0);
    }
    __builtin_amdgcn_s_setprio(0);
  }

  // ---- epilogue ----
  const float inv = 1.0f / lsum;
  float* op = O + ((size_t)h * S_LEN + qrow) * D_DIM;
  #pragma unroll
  for (int dt = 0; dt < 4; ++dt)
    #pragma unroll
    for (int rq = 0; rq < 4; ++rq) {
      f32x4 vv;
      #pragma unroll
      for (int jj = 0; jj < 4; ++jj) vv[jj] = o4[dt][rq * 4 + jj] * inv;
      *(f32x4*)(op + 32 * dt + 8 * rq + 4 * hi) = vv;
    }
}

extern "C" void kernel_launch(void* const* d_in, const int* in_sizes, int n_in,
                              void* d_out, int out_size, void* d_ws, size_t ws_size,
                              hipStream_t stream) {
  const float* Q = (const float*)d_in[0];
  const float* K = (const float*)d_in[1];
  const float* V = (const float*)d_in[2];
  float* O = (float*)d_out;
  ushort* wsK = (ushort*)d_ws;
  ushort* wsV = wsK + (size_t)8 * NT * (KTILE_B / 2);   // +4MB
  prep_k<<<1024, 256, 0, stream>>>(K, wsK);
  prep_v<<<1024, 256, 0, stream>>>(V, wsV);
  attn_fwd<<<2048, 64, 0, stream>>>(Q, wsK, wsV, O);
}

// Round 8
// 82.748 us; speedup vs baseline: 1.5626x; 1.0104x over previous
//
#include <hip/hip_runtime.h>
#include <hip/hip_bf16.h>
#include <stdint.h>

typedef __attribute__((ext_vector_type(8))) short bf16x8;
typedef __attribute__((ext_vector_type(4))) float f32x4;
typedef __attribute__((ext_vector_type(16))) float f32x16;

#define S_LEN 2048
#define D_DIM 128
#define HQ_N  32
#define KVB   32
#define NT    64            // 32-row kv tiles per kv-head
#define KTILE_B 8192        // one tile: 512 chunks x 16B, fragment-ordered
#define VTILE_B 8192

__device__ __forceinline__ ushort f2bf(float f) {
  union { float f; uint32_t u; } c; c.f = f;
  uint32_t u = c.u;
  u += 0x7FFFu + ((u >> 16) & 1u);   // round-nearest-even
  return (ushort)(u >> 16);
}

__device__ __forceinline__ uint32_t cvtpk(float lo, float hi) {
  uint32_t r;
  asm("v_cvt_pk_bf16_f32 %0, %1, %2" : "=v"(r) : "v"(lo), "v"(hi));
  return r;
}

// ---- prep K: fragment-ordered bf16 tiles ----
// tile = hkv*64 + kt. chunk c = s*64 + lane (lane = hi*32 + l31):
//   content = K[tile*32 + l31][16s + 8hi .. +7]
__global__ __launch_bounds__(256) void prep_k(const float* __restrict__ K,
                                              ushort* __restrict__ KT) {
  int tid  = blockIdx.x * 256 + threadIdx.x;   // 262144
  int tile = tid >> 9;
  int c    = tid & 511;
  int s    = c >> 6;
  int lane = c & 63;
  int l31  = lane & 31, hi = lane >> 5;
  const float* src = K + ((size_t)(tile * 32 + l31)) * D_DIM + 16 * s + 8 * hi;
  float4 x = *(const float4*)src;
  float4 y = *(const float4*)(src + 4);
  union { ushort u[8]; bf16x8 v; } o;
  o.u[0] = f2bf(x.x); o.u[1] = f2bf(x.y); o.u[2] = f2bf(x.z); o.u[3] = f2bf(x.w);
  o.u[4] = f2bf(y.x); o.u[5] = f2bf(y.y); o.u[6] = f2bf(y.z); o.u[7] = f2bf(y.w);
  *(bf16x8*)(KT + (size_t)tid * 8) = o.v;
}

// ---- prep V: fragment-ordered transposed bf16 tiles ----
// tile = hkv*64 + kt. chunk cc = dt*128 + c*64 + hi*32 + l31:
//   content = V^T[32dt + l31][kt*32 + 16c + 8hi .. +7]  (gathered stride-D)
__global__ __launch_bounds__(256) void prep_v(const float* __restrict__ V,
                                              ushort* __restrict__ VT) {
  int tid  = blockIdx.x * 256 + threadIdx.x;   // 262144
  int tile = tid >> 9;
  int cc   = tid & 511;
  int l31  = cc & 31;
  int hi   = (cc >> 5) & 1;
  int c    = (cc >> 6) & 1;
  int dt   = cc >> 7;
  int hkv  = tile >> 6, kt = tile & 63;
  const float* src = V + ((size_t)hkv * S_LEN + kt * 32 + 16 * c + 8 * hi) * D_DIM
                       + 32 * dt + l31;
  union { ushort u[8]; bf16x8 v; } o;
  #pragma unroll
  for (int jj = 0; jj < 8; ++jj) o.u[jj] = f2bf(src[(size_t)jj * D_DIM]);
  *(bf16x8*)(VT + (size_t)tid * 8) = o.v;
}

// ---- one kv-tile step; KC = current K frags (preloaded), KN = next (prefetch) ----
__device__ __forceinline__ void step32(
    int kt, int j, int qrow, int hi, int lane,
    const char* kt_base, const char* vt_base,
    const bf16x8 (&qf)[8], bf16x8 (&KC)[8], bf16x8 (&KN)[8],
    f32x16 (&o4)[4], float& mrow, float& lsum) {
  // V loads for THIS tile (used ~500 cyc later in PV)
  bf16x8 vf[8];
  const char* vp = vt_base + (size_t)kt * VTILE_B;
  #pragma unroll
  for (int u = 0; u < 8; ++u)
    vf[u] = *(const bf16x8*)(vp + (u * 64 + lane) * 16);
  // K prefetch for NEXT tile (used next step)
  if (kt < j) {
    const char* kp2 = kt_base + (size_t)(kt + 1) * KTILE_B;
    #pragma unroll
    for (int s = 0; s < 8; ++s)
      KN[s] = *(const bf16x8*)(kp2 + (s * 64 + lane) * 16);
  }

  // ---- S^T = K Q (KC loaded one full step ago) ----
  f32x16 st = {};
  __builtin_amdgcn_s_setprio(1);
  #pragma unroll
  for (int s = 0; s < 8; ++s)
    st = __builtin_amdgcn_mfma_f32_32x32x16_bf16(KC[s], qf[s], st, 0, 0, 0);
  __builtin_amdgcn_s_setprio(0);

  // ---- causal mask (diagonal tile only) ----
  if (kt == j) {
    #pragma unroll
    for (int r = 0; r < 16; ++r) {
      int kv = KVB * kt + (r & 3) + 8 * (r >> 2) + 4 * hi;
      if (kv > qrow) st[r] = -1e30f;
    }
  }

  // ---- online softmax, lane-local rows ----
  float t8[8];
  #pragma unroll
  for (int e = 0; e < 8; ++e) t8[e] = fmaxf(st[e], st[e + 8]);
  float mx = fmaxf(fmaxf(fmaxf(t8[0], t8[1]), fmaxf(t8[2], t8[3])),
                   fmaxf(fmaxf(t8[4], t8[5]), fmaxf(t8[6], t8[7])));
  mx = fmaxf(mx, __shfl_xor(mx, 32));
  // defer-max (T13): rescale only when the running max grew by >8 (log2 domain)
  if (!__all(mx <= mrow + 8.0f)) {
    float mnew = fmaxf(mrow, mx);
    float alpha = exp2f(mrow - mnew);
    #pragma unroll
    for (int dt = 0; dt < 4; ++dt) o4[dt] *= alpha;
    lsum *= alpha;
    mrow = mnew;
  }

  #pragma unroll
  for (int e = 0; e < 16; ++e) st[e] = exp2f(st[e] - mrow);
  float s8[8];
  #pragma unroll
  for (int e = 0; e < 8; ++e) s8[e] = st[e] + st[e + 8];
  float rsum = ((s8[0] + s8[1]) + (s8[2] + s8[3])) +
               ((s8[4] + s8[5]) + (s8[6] + s8[7]));
  rsum += __shfl_xor(rsum, 32);
  lsum += rsum;

  // ---- pack P^T: cvt_pk + permlane32_swap (validated recipe) ----
  bf16x8 pb[2];
  #pragma unroll
  for (int c = 0; c < 2; ++c) {
    const int r0 = c * 8;
    uint32_t a0 = cvtpk(st[r0 + 0], st[r0 + 1]);
    uint32_t b0 = cvtpk(st[r0 + 4], st[r0 + 5]);
    asm volatile("v_permlane32_swap_b32 %0, %1" : "+v"(a0), "+v"(b0));
    uint32_t a1 = cvtpk(st[r0 + 2], st[r0 + 3]);
    uint32_t b1 = cvtpk(st[r0 + 6], st[r0 + 7]);
    asm volatile("v_permlane32_swap_b32 %0, %1" : "+v"(a1), "+v"(b1));
    union { uint32_t u[4]; bf16x8 v; } pu;
    pu.u[0] = a0; pu.u[1] = a1; pu.u[2] = b0; pu.u[3] = b1;
    pb[c] = pu.v;
  }

  // ---- O^T += V^T P^T ----
  __builtin_amdgcn_s_setprio(1);
  #pragma unroll
  for (int dt = 0; dt < 4; ++dt) {
    o4[dt] = __builtin_amdgcn_mfma_f32_32x32x16_bf16(vf[2 * dt + 0], pb[0], o4[dt], 0, 0, 0);
    o4[dt] = __builtin_amdgcn_mfma_f32_32x32x16_bf16(vf[2 * dt + 1], pb[1], o4[dt], 0, 0, 0);
  }
  __builtin_amdgcn_s_setprio(0);
}

// ---- flash attention: 1-wave blocks, no LDS, K reg-double-buffered ----
__global__ __launch_bounds__(64, 2) void attn_fwd(
    const float* __restrict__ Q, const ushort* __restrict__ KT,
    const ushort* __restrict__ VT, float* __restrict__ O) {
  const int id   = blockIdx.x;           // 2048 blocks
  const int g    = id & 7;               // kv-head -> XCD affinity
  const int rest = id >> 3;
  const int qh   = rest & 3;
  const int j    = 63 - (rest >> 2);     // longest first
  const int h    = g * 4 + qh;
  const int lane = threadIdx.x;
  const int l31  = lane & 31;
  const int hi   = lane >> 5;
  const int qrow = j * 32 + l31;

  const char* kt_base = (const char*)KT + (size_t)g * NT * KTILE_B;
  const char* vt_base = (const char*)VT + (size_t)g * NT * VTILE_B;

  // Q fragments (B operand), log2-domain scale
  const float scale = 0.08838834764831845f * 1.4426950408889634f;
  bf16x8 qf[8];
  {
    const float* qp = Q + ((size_t)h * S_LEN + qrow) * D_DIM;
    #pragma unroll
    for (int s = 0; s < 8; ++s) {
      const float* p = qp + 16 * s + 8 * hi;
      float4 x = *(const float4*)p;
      float4 y = *(const float4*)(p + 4);
      bf16x8 f;
      f[0] = (short)f2bf(x.x * scale); f[1] = (short)f2bf(x.y * scale);
      f[2] = (short)f2bf(x.z * scale); f[3] = (short)f2bf(x.w * scale);
      f[4] = (short)f2bf(y.x * scale); f[5] = (short)f2bf(y.y * scale);
      f[6] = (short)f2bf(y.z * scale); f[7] = (short)f2bf(y.w * scale);
      qf[s] = f;
    }
  }

  f32x16 o4[4] = {};       // O^T: q=l31, d = 32*dt + (r&3)+8*(r>>2)+4*hi
  float mrow = -1e30f, lsum = 0.f;

  // preload K tile 0 into set A
  bf16x8 kfa[8], kfb[8];
  #pragma unroll
  for (int s = 0; s < 8; ++s)
    kfa[s] = *(const bf16x8*)(kt_base + (s * 64 + lane) * 16);

  // manual 2x unroll keeps the two K register sets statically indexed
  int kt = 0;
  for (;;) {
    step32(kt, j, qrow, hi, lane, kt_base, vt_base, qf, kfa, kfb, o4, mrow, lsum);
    if (++kt > j) break;
    step32(kt, j, qrow, hi, lane, kt_base, vt_base, qf, kfb, kfa, o4, mrow, lsum);
    if (++kt > j) break;
  }

  // ---- epilogue ----
  const float inv = 1.0f / lsum;
  float* op = O + ((size_t)h * S_LEN + qrow) * D_DIM;
  #pragma unroll
  for (int dt = 0; dt < 4; ++dt)
    #pragma unroll
    for (int rq = 0; rq < 4; ++rq) {
      f32x4 vv;
      #pragma unroll
      for (int jj = 0; jj < 4; ++jj) vv[jj] = o4[dt][rq * 4 + jj] * inv;
      *(f32x4*)(op + 32 * dt + 8 * rq + 4 * hi) = vv;
    }
}

extern "C" void kernel_launch(void* const* d_in, const int* in_sizes, int n_in,
                              void* d_out, int out_size, void* d_ws, size_t ws_size,
                              hipStream_t stream) {
  const float* Q = (const float*)d_in[0];
  const float* K = (const float*)d_in[1];
  const float* V = (const float*)d_in[2];
  float* O = (float*)d_out;
  ushort* wsK = (ushort*)d_ws;
  ushort* wsV = wsK + (size_t)8 * NT * (KTILE_B / 2);   // +4MB
  prep_k<<<1024, 256, 0, stream>>>(K, wsK);
  prep_v<<<1024, 256, 0, stream>>>(V, wsV);
  attn_fwd<<<2048, 64, 0, stream>>>(Q, wsK, wsV, O);
}

// Round 9
// 82.433 us; speedup vs baseline: 1.5685x; 1.0038x over previous
//
#include <hip/hip_runtime.h>
#include <hip/hip_bf16.h>
#include <stdint.h>

typedef __attribute__((ext_vector_type(8))) short bf16x8;
typedef __attribute__((ext_vector_type(4))) float f32x4;
typedef __attribute__((ext_vector_type(16))) float f32x16;

#define S_LEN 2048
#define D_DIM 128
#define HQ_N  32
#define KVB   32
#define NT    64            // 32-row kv tiles per kv-head
#define KTILE_B 8192        // one tile: 512 chunks x 16B, fragment-ordered
#define VTILE_B 8192

__device__ __forceinline__ ushort f2bf(float f) {
  union { float f; uint32_t u; } c; c.f = f;
  uint32_t u = c.u;
  u += 0x7FFFu + ((u >> 16) & 1u);   // round-nearest-even
  return (ushort)(u >> 16);
}

__device__ __forceinline__ uint32_t cvtpk(float lo, float hi) {
  uint32_t r;
  asm("v_cvt_pk_bf16_f32 %0, %1, %2" : "=v"(r) : "v"(lo), "v"(hi));
  return r;
}

// cross-half (lane ^32) reduce-max via permlane32_swap: VALU-only, no DS.
// b is forced into a DISTINCT register ("=&v" mov) before the swap — the
// R5 failure was copy-propagation collapsing a,b into one physical reg.
__device__ __forceinline__ float xhalf_max(float x) {
  uint32_t a = __builtin_bit_cast(uint32_t, x), b;
  asm volatile("v_mov_b32 %0, %1" : "=&v"(b) : "v"(a));
  asm volatile("v_permlane32_swap_b32 %0, %1" : "+v"(a), "+v"(b));
  return fmaxf(__builtin_bit_cast(float, a), __builtin_bit_cast(float, b));
}

// ---- prep K: fragment-ordered bf16 tiles ----
// tile = hkv*64 + kt. chunk c = s*64 + lane (lane = hi*32 + l31):
//   content = K[tile*32 + l31][16s + 8hi .. +7]
__global__ __launch_bounds__(256) void prep_k(const float* __restrict__ K,
                                              ushort* __restrict__ KT) {
  int tid  = blockIdx.x * 256 + threadIdx.x;   // 262144
  int tile = tid >> 9;
  int c    = tid & 511;
  int s    = c >> 6;
  int lane = c & 63;
  int l31  = lane & 31, hi = lane >> 5;
  const float* src = K + ((size_t)(tile * 32 + l31)) * D_DIM + 16 * s + 8 * hi;
  float4 x = *(const float4*)src;
  float4 y = *(const float4*)(src + 4);
  union { ushort u[8]; bf16x8 v; } o;
  o.u[0] = f2bf(x.x); o.u[1] = f2bf(x.y); o.u[2] = f2bf(x.z); o.u[3] = f2bf(x.w);
  o.u[4] = f2bf(y.x); o.u[5] = f2bf(y.y); o.u[6] = f2bf(y.z); o.u[7] = f2bf(y.w);
  *(bf16x8*)(KT + (size_t)tid * 8) = o.v;
}

// ---- prep V: fragment-ordered transposed bf16 tiles ----
// tile = hkv*64 + kt. chunk cc = dt*128 + c*64 + hi*32 + l31:
//   content = V^T[32dt + l31][kt*32 + 16c + 8hi .. +7]  (gathered stride-D)
__global__ __launch_bounds__(256) void prep_v(const float* __restrict__ V,
                                              ushort* __restrict__ VT) {
  int tid  = blockIdx.x * 256 + threadIdx.x;   // 262144
  int tile = tid >> 9;
  int cc   = tid & 511;
  int l31  = cc & 31;
  int hi   = (cc >> 5) & 1;
  int c    = (cc >> 6) & 1;
  int dt   = cc >> 7;
  int hkv  = tile >> 6, kt = tile & 63;
  const float* src = V + ((size_t)hkv * S_LEN + kt * 32 + 16 * c + 8 * hi) * D_DIM
                       + 32 * dt + l31;
  union { ushort u[8]; bf16x8 v; } o;
  #pragma unroll
  for (int jj = 0; jj < 8; ++jj) o.u[jj] = f2bf(src[(size_t)jj * D_DIM]);
  *(bf16x8*)(VT + (size_t)tid * 8) = o.v;
}

// ---- one kv-tile step; KC = current K frags (preloaded), KN = next (prefetch) ----
__device__ __forceinline__ void step32(
    int kt, int j, int qrow, int hi, int lane,
    const char* kt_base, const char* vt_base,
    const bf16x8 (&qf)[8], bf16x8 (&KC)[8], bf16x8 (&KN)[8],
    const bf16x8& ones, const f32x16& zero16,
    f32x16 (&o4)[4], float& mrow, float& lsum) {
  // V loads for THIS tile (used ~500 cyc later in PV)
  bf16x8 vf[8];
  const char* vp = vt_base + (size_t)kt * VTILE_B;
  #pragma unroll
  for (int u = 0; u < 8; ++u)
    vf[u] = *(const bf16x8*)(vp + (u * 64 + lane) * 16);
  // K prefetch for NEXT tile (used next step)
  if (kt < j) {
    const char* kp2 = kt_base + (size_t)(kt + 1) * KTILE_B;
    #pragma unroll
    for (int s = 0; s < 8; ++s)
      KN[s] = *(const bf16x8*)(kp2 + (s * 64 + lane) * 16);
  }

  // ---- S^T = K Q (KC loaded one full step ago) ----
  f32x16 st = {};
  __builtin_amdgcn_s_setprio(1);
  #pragma unroll
  for (int s = 0; s < 8; ++s)
    st = __builtin_amdgcn_mfma_f32_32x32x16_bf16(KC[s], qf[s], st, 0, 0, 0);
  __builtin_amdgcn_s_setprio(0);

  // ---- causal mask (diagonal tile only) ----
  if (kt == j) {
    #pragma unroll
    for (int r = 0; r < 16; ++r) {
      int kv = KVB * kt + (r & 3) + 8 * (r >> 2) + 4 * hi;
      if (kv > qrow) st[r] = -1e30f;
    }
  }

  // ---- online softmax, lane-local rows; cross-half max via permlane ----
  float t8[8];
  #pragma unroll
  for (int e = 0; e < 8; ++e) t8[e] = fmaxf(st[e], st[e + 8]);
  float mx = fmaxf(fmaxf(fmaxf(t8[0], t8[1]), fmaxf(t8[2], t8[3])),
                   fmaxf(fmaxf(t8[4], t8[5]), fmaxf(t8[6], t8[7])));
  mx = xhalf_max(mx);
  // defer-max (T13): rescale only when the running max grew by >8 (log2 domain)
  if (!__all(mx <= mrow + 8.0f)) {
    float mnew = fmaxf(mrow, mx);
    float alpha = exp2f(mrow - mnew);
    #pragma unroll
    for (int dt = 0; dt < 4; ++dt) o4[dt] *= alpha;
    lsum *= alpha;
    mrow = mnew;
  }

  #pragma unroll
  for (int e = 0; e < 16; ++e) st[e] = exp2f(st[e] - mrow);

  // ---- pack P^T: cvt_pk + permlane32_swap (validated recipe) ----
  bf16x8 pb[2];
  #pragma unroll
  for (int c = 0; c < 2; ++c) {
    const int r0 = c * 8;
    uint32_t a0 = cvtpk(st[r0 + 0], st[r0 + 1]);
    uint32_t b0 = cvtpk(st[r0 + 4], st[r0 + 5]);
    asm volatile("v_permlane32_swap_b32 %0, %1" : "+v"(a0), "+v"(b0));
    uint32_t a1 = cvtpk(st[r0 + 2], st[r0 + 3]);
    uint32_t b1 = cvtpk(st[r0 + 6], st[r0 + 7]);
    asm volatile("v_permlane32_swap_b32 %0, %1" : "+v"(a1), "+v"(b1));
    union { uint32_t u[4]; bf16x8 v; } pu;
    pu.u[0] = a0; pu.u[1] = a1; pu.u[2] = b0; pu.u[3] = b1;
    pb[c] = pu.v;
  }

  // ---- row-sum of P via ones-MFMA: D[any][q] = sum_kv P[q][kv] ----
  f32x16 pbsum = __builtin_amdgcn_mfma_f32_32x32x16_bf16(ones, pb[0], zero16, 0, 0, 0);
  pbsum = __builtin_amdgcn_mfma_f32_32x32x16_bf16(ones, pb[1], pbsum, 0, 0, 0);

  // ---- O^T += V^T P^T ----
  __builtin_amdgcn_s_setprio(1);
  #pragma unroll
  for (int dt = 0; dt < 4; ++dt) {
    o4[dt] = __builtin_amdgcn_mfma_f32_32x32x16_bf16(vf[2 * dt + 0], pb[0], o4[dt], 0, 0, 0);
    o4[dt] = __builtin_amdgcn_mfma_f32_32x32x16_bf16(vf[2 * dt + 1], pb[1], o4[dt], 0, 0, 0);
  }
  __builtin_amdgcn_s_setprio(0);

  lsum += pbsum[0];
}

// ---- flash attention: 1-wave blocks, no LDS, K reg-double-buffered ----
__global__ __launch_bounds__(64, 2) void attn_fwd(
    const float* __restrict__ Q, const ushort* __restrict__ KT,
    const ushort* __restrict__ VT, float* __restrict__ O) {
  const int id   = blockIdx.x;           // 2048 blocks
  const int g    = id & 7;               // kv-head -> XCD affinity
  const int rest = id >> 3;
  const int qh   = rest & 3;
  const int j    = 63 - (rest >> 2);     // longest first
  const int h    = g * 4 + qh;
  const int lane = threadIdx.x;
  const int l31  = lane & 31;
  const int hi   = lane >> 5;
  const int qrow = j * 32 + l31;

  const char* kt_base = (const char*)KT + (size_t)g * NT * KTILE_B;
  const char* vt_base = (const char*)VT + (size_t)g * NT * VTILE_B;

  // Q fragments (B operand), log2-domain scale
  const float scale = 0.08838834764831845f * 1.4426950408889634f;
  bf16x8 qf[8];
  {
    const float* qp = Q + ((size_t)h * S_LEN + qrow) * D_DIM;
    #pragma unroll
    for (int s = 0; s < 8; ++s) {
      const float* p = qp + 16 * s + 8 * hi;
      float4 x = *(const float4*)p;
      float4 y = *(const float4*)(p + 4);
      bf16x8 f;
      f[0] = (short)f2bf(x.x * scale); f[1] = (short)f2bf(x.y * scale);
      f[2] = (short)f2bf(x.z * scale); f[3] = (short)f2bf(x.w * scale);
      f[4] = (short)f2bf(y.x * scale); f[5] = (short)f2bf(y.y * scale);
      f[6] = (short)f2bf(y.z * scale); f[7] = (short)f2bf(y.w * scale);
      qf[s] = f;
    }
  }

  bf16x8 ones;
  #pragma unroll
  for (int s = 0; s < 8; ++s) ones[s] = (short)0x3F80;   // bf16 1.0
  const f32x16 zero16 = {};

  f32x16 o4[4] = {};       // O^T: q=l31, d = 32*dt + (r&3)+8*(r>>2)+4*hi
  float mrow = -1e30f, lsum = 0.f;

  // preload K tile 0 into set A
  bf16x8 kfa[8], kfb[8];
  #pragma unroll
  for (int s = 0; s < 8; ++s)
    kfa[s] = *(const bf16x8*)(kt_base + (s * 64 + lane) * 16);

  // manual 2x unroll keeps the two K register sets statically indexed
  int kt = 0;
  for (;;) {
    step32(kt, j, qrow, hi, lane, kt_base, vt_base, qf, kfa, kfb, ones, zero16,
           o4, mrow, lsum);
    if (++kt > j) break;
    step32(kt, j, qrow, hi, lane, kt_base, vt_base, qf, kfb, kfa, ones, zero16,
           o4, mrow, lsum);
    if (++kt > j) break;
  }

  // ---- epilogue ----
  const float inv = 1.0f / lsum;
  float* op = O + ((size_t)h * S_LEN + qrow) * D_DIM;
  #pragma unroll
  for (int dt = 0; dt < 4; ++dt)
    #pragma unroll
    for (int rq = 0; rq < 4; ++rq) {
      f32x4 vv;
      #pragma unroll
      for (int jj = 0; jj < 4; ++jj) vv[jj] = o4[dt][rq * 4 + jj] * inv;
      *(f32x4*)(op + 32 * dt + 8 * rq + 4 * hi) = vv;
    }
}

extern "C" void kernel_launch(void* const* d_in, const int* in_sizes, int n_in,
                              void* d_out, int out_size, void* d_ws, size_t ws_size,
                              hipStream_t stream) {
  const float* Q = (const float*)d_in[0];
  const float* K = (const float*)d_in[1];
  const float* V = (const float*)d_in[2];
  float* O = (float*)d_out;
  ushort* wsK = (ushort*)d_ws;
  ushort* wsV = wsK + (size_t)8 * NT * (KTILE_B / 2);   // +4MB
  prep_k<<<1024, 256, 0, stream>>>(K, wsK);
  prep_v<<<1024, 256, 0, stream>>>(V, wsV);
  attn_fwd<<<2048, 64, 0, stream>>>(Q, wsK, wsV, O);
}

// Round 10
// 82.419 us; speedup vs baseline: 1.5688x; 1.0002x over previous
//
#include <hip/hip_runtime.h>
#include <hip/hip_bf16.h>
#include <stdint.h>

typedef __attribute__((ext_vector_type(8))) short bf16x8;
typedef __attribute__((ext_vector_type(4))) float f32x4;
typedef __attribute__((ext_vector_type(16))) float f32x16;

#define S_LEN 2048
#define D_DIM 128
#define HQ_N  32
#define NT32  64            // 32-row kv subtiles per kv-head
#define SUB_B 8192          // 32-row subtile bytes (512 chunks x 16B)

__device__ __forceinline__ ushort f2bf(float f) {
  union { float f; uint32_t u; } c; c.f = f;
  uint32_t u = c.u;
  u += 0x7FFFu + ((u >> 16) & 1u);   // round-nearest-even
  return (ushort)(u >> 16);
}

__device__ __forceinline__ uint32_t cvtpk(float lo, float hi) {
  uint32_t r;
  asm("v_cvt_pk_bf16_f32 %0, %1, %2" : "=v"(r) : "v"(lo), "v"(hi));
  return r;
}

// cross-half (lane^32) max via permlane32_swap, VALU-only (validated R9)
__device__ __forceinline__ float xhalf_max(float x) {
  uint32_t a = __builtin_bit_cast(uint32_t, x), b;
  asm volatile("v_mov_b32 %0, %1" : "=&v"(b) : "v"(a));
  asm volatile("v_permlane32_swap_b32 %0, %1" : "+v"(a), "+v"(b));
  return fmaxf(__builtin_bit_cast(float, a), __builtin_bit_cast(float, b));
}

// ---- prep K: fragment-ordered bf16 subtiles (UNCHANGED layout from R7-R9) ----
// subtile = hkv*64 + ktv (32 kv rows). chunk c = s*64 + lane:
//   content = K[subtile*32 + l31][16s + 8hi .. +7]
__global__ __launch_bounds__(256) void prep_k(const float* __restrict__ K,
                                              ushort* __restrict__ KT) {
  int tid  = blockIdx.x * 256 + threadIdx.x;   // 262144
  int tile = tid >> 9;
  int c    = tid & 511;
  int s    = c >> 6;
  int lane = c & 63;
  int l31  = lane & 31, hi = lane >> 5;
  const float* src = K + ((size_t)(tile * 32 + l31)) * D_DIM + 16 * s + 8 * hi;
  float4 x = *(const float4*)src;
  float4 y = *(const float4*)(src + 4);
  union { ushort u[8]; bf16x8 v; } o;
  o.u[0] = f2bf(x.x); o.u[1] = f2bf(x.y); o.u[2] = f2bf(x.z); o.u[3] = f2bf(x.w);
  o.u[4] = f2bf(y.x); o.u[5] = f2bf(y.y); o.u[6] = f2bf(y.z); o.u[7] = f2bf(y.w);
  *(bf16x8*)(KT + (size_t)tid * 8) = o.v;
}

// ---- prep V: fragment-ordered transposed subtiles (UNCHANGED from R7-R9) ----
// subtile = hkv*64 + ktv. chunk cc = dt*128 + c*64 + lane:
//   content = V^T[32dt + l31][ktv*32 + 16c + 8hi .. +7]
__global__ __launch_bounds__(256) void prep_v(const float* __restrict__ V,
                                              ushort* __restrict__ VT) {
  int tid  = blockIdx.x * 256 + threadIdx.x;   // 262144
  int tile = tid >> 9;
  int cc   = tid & 511;
  int l31  = cc & 31;
  int hi   = (cc >> 5) & 1;
  int c    = (cc >> 6) & 1;
  int dt   = cc >> 7;
  int hkv  = tile >> 6, ktv = tile & 63;
  const float* src = V + ((size_t)hkv * S_LEN + ktv * 32 + 16 * c + 8 * hi) * D_DIM
                       + 32 * dt + l31;
  union { ushort u[8]; bf16x8 v; } o;
  #pragma unroll
  for (int jj = 0; jj < 8; ++jj) o.u[jj] = f2bf(src[(size_t)jj * D_DIM]);
  *(bf16x8*)(VT + (size_t)tid * 8) = o.v;
}

// ---- flash attention: 1-wave blocks, no LDS, KVB=64 per step ----
__global__ __launch_bounds__(64, 2) void attn_fwd(
    const float* __restrict__ Q, const ushort* __restrict__ KT,
    const ushort* __restrict__ VT, float* __restrict__ O) {
  const int id   = blockIdx.x;           // 2048 blocks
  const int g    = id & 7;               // kv-head -> XCD affinity
  const int rest = id >> 3;
  const int qh   = rest & 3;
  const int j    = 63 - (rest >> 2);     // q-tile (32 rows), longest first
  const int h    = g * 4 + qh;
  const int lane = threadIdx.x;
  const int l31  = lane & 31;
  const int hi   = lane >> 5;
  const int qrow = j * 32 + l31;
  const int jt   = j >> 1;               // last 64-row kv tile index

  const char* kt_base = (const char*)KT + (size_t)g * NT32 * SUB_B;
  const char* vt_base = (const char*)VT + (size_t)g * NT32 * SUB_B;

  // Q fragments (B operand), log2-domain scale
  const float scale = 0.08838834764831845f * 1.4426950408889634f;
  bf16x8 qf[8];
  {
    const float* qp = Q + ((size_t)h * S_LEN + qrow) * D_DIM;
    #pragma unroll
    for (int s = 0; s < 8; ++s) {
      const float* p = qp + 16 * s + 8 * hi;
      float4 x = *(const float4*)p;
      float4 y = *(const float4*)(p + 4);
      bf16x8 f;
      f[0] = (short)f2bf(x.x * scale); f[1] = (short)f2bf(x.y * scale);
      f[2] = (short)f2bf(x.z * scale); f[3] = (short)f2bf(x.w * scale);
      f[4] = (short)f2bf(y.x * scale); f[5] = (short)f2bf(y.y * scale);
      f[6] = (short)f2bf(y.z * scale); f[7] = (short)f2bf(y.w * scale);
      qf[s] = f;
    }
  }

  bf16x8 ones;
  #pragma unroll
  for (int s = 0; s < 8; ++s) ones[s] = (short)0x3F80;   // bf16 1.0
  const f32x16 zero16 = {};

  f32x16 o4[4] = {};       // O^T: q=l31, d = 32*dt + (r&3)+8*(r>>2)+4*hi
  float mrow = -1e30f, lsum = 0.f;

  for (int kt = 0; kt <= jt; ++kt) {
    const char* kp = kt_base + (size_t)kt * (2 * SUB_B);

    // ---- issue K (16 frags) + V first half (ks=0,1 -> 8 frags) ----
    bf16x8 kf[16];
    #pragma unroll
    for (int t = 0; t < 2; ++t)
      #pragma unroll
      for (int s = 0; s < 8; ++s)
        kf[t * 8 + s] = *(const bf16x8*)(kp + t * SUB_B + (s * 64 + lane) * 16);
    bf16x8 vfA[8], vfB[8];
    const char* vp = vt_base + (size_t)(2 * kt) * SUB_B;
    #pragma unroll
    for (int ks = 0; ks < 2; ++ks)
      #pragma unroll
      for (int dt = 0; dt < 4; ++dt)
        vfA[ks * 4 + dt] = *(const bf16x8*)(vp + (dt * 128 + ks * 64 + lane) * 16);

    // ---- S^T = K Q (2 kv-subtiles) ----
    f32x16 st[2] = {};
    __builtin_amdgcn_s_setprio(1);
    #pragma unroll
    for (int t = 0; t < 2; ++t)
      #pragma unroll
      for (int s = 0; s < 8; ++s)
        st[t] = __builtin_amdgcn_mfma_f32_32x32x16_bf16(kf[t * 8 + s], qf[s], st[t], 0, 0, 0);
    __builtin_amdgcn_s_setprio(0);

    // ---- issue V second half (ks=2,3); lands during softmax ----
    #pragma unroll
    for (int ks = 0; ks < 2; ++ks)
      #pragma unroll
      for (int dt = 0; dt < 4; ++dt)
        vfB[ks * 4 + dt] = *(const bf16x8*)(vp + SUB_B + (dt * 128 + ks * 64 + lane) * 16);

    // ---- causal mask (diagonal 64-tile only) ----
    if (kt == jt) {
      #pragma unroll
      for (int t = 0; t < 2; ++t)
        #pragma unroll
        for (int r = 0; r < 16; ++r) {
          int kv = 64 * kt + 32 * t + (r & 3) + 8 * (r >> 2) + 4 * hi;
          if (kv > qrow) st[t][r] = -1e30f;
        }
    }

    // ---- online softmax over 32 lane-local values ----
    float t16[8];
    #pragma unroll
    for (int e = 0; e < 8; ++e)
      t16[e] = fmaxf(fmaxf(st[0][e], st[0][e + 8]), fmaxf(st[1][e], st[1][e + 8]));
    float mx = fmaxf(fmaxf(fmaxf(t16[0], t16[1]), fmaxf(t16[2], t16[3])),
                     fmaxf(fmaxf(t16[4], t16[5]), fmaxf(t16[6], t16[7])));
    mx = xhalf_max(mx);
    // defer-max (T13, validated R8/R9)
    if (!__all(mx <= mrow + 8.0f)) {
      float mnew = fmaxf(mrow, mx);
      float alpha = exp2f(mrow - mnew);
      #pragma unroll
      for (int dt = 0; dt < 4; ++dt) o4[dt] *= alpha;
      lsum *= alpha;
      mrow = mnew;
    }
    #pragma unroll
    for (int t = 0; t < 2; ++t)
      #pragma unroll
      for (int e = 0; e < 16; ++e) st[t][e] = exp2f(st[t][e] - mrow);

    // ---- pack P^T (validated recipe, per kv-subtile) ----
    bf16x8 pb[4];
    #pragma unroll
    for (int t = 0; t < 2; ++t)
      #pragma unroll
      for (int c = 0; c < 2; ++c) {
        const int r0 = c * 8;
        uint32_t a0 = cvtpk(st[t][r0 + 0], st[t][r0 + 1]);
        uint32_t b0 = cvtpk(st[t][r0 + 4], st[t][r0 + 5]);
        asm volatile("v_permlane32_swap_b32 %0, %1" : "+v"(a0), "+v"(b0));
        uint32_t a1 = cvtpk(st[t][r0 + 2], st[t][r0 + 3]);
        uint32_t b1 = cvtpk(st[t][r0 + 6], st[t][r0 + 7]);
        asm volatile("v_permlane32_swap_b32 %0, %1" : "+v"(a1), "+v"(b1));
        union { uint32_t u[4]; bf16x8 v; } pu;
        pu.u[0] = a0; pu.u[1] = a1; pu.u[2] = b0; pu.u[3] = b1;
        pb[t * 2 + c] = pu.v;
      }

    // ---- row-sum of P via ones-MFMA ----
    f32x16 pbsum = __builtin_amdgcn_mfma_f32_32x32x16_bf16(ones, pb[0], zero16, 0, 0, 0);
    pbsum = __builtin_amdgcn_mfma_f32_32x32x16_bf16(ones, pb[1], pbsum, 0, 0, 0);
    pbsum = __builtin_amdgcn_mfma_f32_32x32x16_bf16(ones, pb[2], pbsum, 0, 0, 0);
    pbsum = __builtin_amdgcn_mfma_f32_32x32x16_bf16(ones, pb[3], pbsum, 0, 0, 0);

    // ---- O^T += V^T P^T (4 k-slices of 16) ----
    __builtin_amdgcn_s_setprio(1);
    #pragma unroll
    for (int dt = 0; dt < 4; ++dt) {
      o4[dt] = __builtin_amdgcn_mfma_f32_32x32x16_bf16(vfA[0 * 4 + dt], pb[0], o4[dt], 0, 0, 0);
      o4[dt] = __builtin_amdgcn_mfma_f32_32x32x16_bf16(vfA[1 * 4 + dt], pb[1], o4[dt], 0, 0, 0);
      o4[dt] = __builtin_amdgcn_mfma_f32_32x32x16_bf16(vfB[0 * 4 + dt], pb[2], o4[dt], 0, 0, 0);
      o4[dt] = __builtin_amdgcn_mfma_f32_32x32x16_bf16(vfB[1 * 4 + dt], pb[3], o4[dt], 0, 0, 0);
    }
    __builtin_amdgcn_s_setprio(0);

    lsum += pbsum[0];
  }

  // ---- epilogue ----
  const float inv = 1.0f / lsum;
  float* op = O + ((size_t)h * S_LEN + qrow) * D_DIM;
  #pragma unroll
  for (int dt = 0; dt < 4; ++dt)
    #pragma unroll
    for (int rq = 0; rq < 4; ++rq) {
      f32x4 vv;
      #pragma unroll
      for (int jj = 0; jj < 4; ++jj) vv[jj] = o4[dt][rq * 4 + jj] * inv;
      *(f32x4*)(op + 32 * dt + 8 * rq + 4 * hi) = vv;
    }
}

extern "C" void kernel_launch(void* const* d_in, const int* in_sizes, int n_in,
                              void* d_out, int out_size, void* d_ws, size_t ws_size,
                              hipStream_t stream) {
  const float* Q = (const float*)d_in[0];
  const float* K = (const float*)d_in[1];
  const float* V = (const float*)d_in[2];
  float* O = (float*)d_out;
  ushort* wsK = (ushort*)d_ws;
  ushort* wsV = wsK + (size_t)8 * NT32 * (SUB_B / 2);   // +4MB
  prep_k<<<1024, 256, 0, stream>>>(K, wsK);
  prep_v<<<1024, 256, 0, stream>>>(V, wsV);
  attn_fwd<<<2048, 64, 0, stream>>>(Q, wsK, wsV, O);
}

// Round 11
// 74.656 us; speedup vs baseline: 1.7319x; 1.1040x over previous
//
#include <hip/hip_runtime.h>
#include <hip/hip_bf16.h>
#include <stdint.h>

typedef __attribute__((ext_vector_type(8))) short bf16x8;
typedef __attribute__((ext_vector_type(4))) float f32x4;
typedef __attribute__((ext_vector_type(16))) float f32x16;

#define S_LEN 2048
#define D_DIM 128
#define HQ_N  32
#define NT32  64            // 32-row kv subtiles per kv-head
#define SUB_B 8192          // 32-row subtile bytes (512 chunks x 16B)

__device__ __forceinline__ ushort f2bf(float f) {
  union { float f; uint32_t u; } c; c.f = f;
  uint32_t u = c.u;
  u += 0x7FFFu + ((u >> 16) & 1u);   // round-nearest-even
  return (ushort)(u >> 16);
}

__device__ __forceinline__ uint32_t cvtpk(float lo, float hi) {
  uint32_t r;
  asm("v_cvt_pk_bf16_f32 %0, %1, %2" : "=v"(r) : "v"(lo), "v"(hi));
  return r;
}

// cross-half (lane^32) max via permlane32_swap, VALU-only (validated R9)
__device__ __forceinline__ float xhalf_max(float x) {
  uint32_t a = __builtin_bit_cast(uint32_t, x), b;
  asm volatile("v_mov_b32 %0, %1" : "=&v"(b) : "v"(a));
  asm volatile("v_permlane32_swap_b32 %0, %1" : "+v"(a), "+v"(b));
  return fmaxf(__builtin_bit_cast(float, a), __builtin_bit_cast(float, b));
}

// ---- prep K: fragment-ordered bf16 subtiles (layout unchanged R7-R10) ----
__global__ __launch_bounds__(256) void prep_k(const float* __restrict__ K,
                                              ushort* __restrict__ KT) {
  int tid  = blockIdx.x * 256 + threadIdx.x;   // 262144
  int tile = tid >> 9;
  int c    = tid & 511;
  int s    = c >> 6;
  int lane = c & 63;
  int l31  = lane & 31, hi = lane >> 5;
  const float* src = K + ((size_t)(tile * 32 + l31)) * D_DIM + 16 * s + 8 * hi;
  float4 x = *(const float4*)src;
  float4 y = *(const float4*)(src + 4);
  union { ushort u[8]; bf16x8 v; } o;
  o.u[0] = f2bf(x.x); o.u[1] = f2bf(x.y); o.u[2] = f2bf(x.z); o.u[3] = f2bf(x.w);
  o.u[4] = f2bf(y.x); o.u[5] = f2bf(y.y); o.u[6] = f2bf(y.z); o.u[7] = f2bf(y.w);
  *(bf16x8*)(KT + (size_t)tid * 8) = o.v;
}

// ---- prep V: fragment-ordered transposed subtiles (unchanged R7-R10) ----
__global__ __launch_bounds__(256) void prep_v(const float* __restrict__ V,
                                              ushort* __restrict__ VT) {
  int tid  = blockIdx.x * 256 + threadIdx.x;   // 262144
  int tile = tid >> 9;
  int cc   = tid & 511;
  int l31  = cc & 31;
  int hi   = (cc >> 5) & 1;
  int c    = (cc >> 6) & 1;
  int dt   = cc >> 7;
  int hkv  = tile >> 6, ktv = tile & 63;
  const float* src = V + ((size_t)hkv * S_LEN + ktv * 32 + 16 * c + 8 * hi) * D_DIM
                       + 32 * dt + l31;
  union { ushort u[8]; bf16x8 v; } o;
  #pragma unroll
  for (int jj = 0; jj < 8; ++jj) o.u[jj] = f2bf(src[(size_t)jj * D_DIM]);
  *(bf16x8*)(VT + (size_t)tid * 8) = o.v;
}

// ---- flash attention: 1-wave blocks, no LDS, KVB=64; quad-lockstep remap ----
__global__ __launch_bounds__(64, 2) void attn_fwd(
    const float* __restrict__ Q, const ushort* __restrict__ KT,
    const ushort* __restrict__ VT, float* __restrict__ O) {
  const int id   = blockIdx.x;           // 2048 blocks
  // Quad-lockstep mapping: dispatch model XCD=id%8, CU=(id>>3)%32, round=id>>8.
  // A CU's 8 blocks = 4 q-heads x {j=c, j=63-c}: two lockstep quads sharing the
  // same KV line stream (MSHR/L1 merge), per-CU work balanced (c + 63-c const).
  const int g    = id & 7;               // kv-head == XCD
  const int c    = (id >> 3) & 31;       // CU slot
  const int qh   = (id >> 8) & 3;
  const int p    = (id >> 10) & 1;
  const int j    = p ? (63 - c) : c;     // q-tile (32 rows)
  const int h    = g * 4 + qh;
  const int lane = threadIdx.x;
  const int l31  = lane & 31;
  const int hi   = lane >> 5;
  const int qrow = j * 32 + l31;
  const int jt   = j >> 1;               // last 64-row kv tile index

  const char* kt_base = (const char*)KT + (size_t)g * NT32 * SUB_B;
  const char* vt_base = (const char*)VT + (size_t)g * NT32 * SUB_B;

  // Q fragments (B operand), log2-domain scale
  const float scale = 0.08838834764831845f * 1.4426950408889634f;
  bf16x8 qf[8];
  {
    const float* qp = Q + ((size_t)h * S_LEN + qrow) * D_DIM;
    #pragma unroll
    for (int s = 0; s < 8; ++s) {
      const float* px = qp + 16 * s + 8 * hi;
      float4 x = *(const float4*)px;
      float4 y = *(const float4*)(px + 4);
      bf16x8 f;
      f[0] = (short)f2bf(x.x * scale); f[1] = (short)f2bf(x.y * scale);
      f[2] = (short)f2bf(x.z * scale); f[3] = (short)f2bf(x.w * scale);
      f[4] = (short)f2bf(y.x * scale); f[5] = (short)f2bf(y.y * scale);
      f[6] = (short)f2bf(y.z * scale); f[7] = (short)f2bf(y.w * scale);
      qf[s] = f;
    }
  }

  bf16x8 ones;
  #pragma unroll
  for (int s = 0; s < 8; ++s) ones[s] = (short)0x3F80;   // bf16 1.0
  const f32x16 zero16 = {};

  f32x16 o4[4] = {};       // O^T: q=l31, d = 32*dt + (r&3)+8*(r>>2)+4*hi
  float mrow = -1e30f, lsum = 0.f;

  for (int kt = 0; kt <= jt; ++kt) {
    const char* kp = kt_base + (size_t)kt * (2 * SUB_B);

    // ---- issue K (16 frags) + V first half (8 frags) ----
    bf16x8 kf[16];
    #pragma unroll
    for (int t = 0; t < 2; ++t)
      #pragma unroll
      for (int s = 0; s < 8; ++s)
        kf[t * 8 + s] = *(const bf16x8*)(kp + t * SUB_B + (s * 64 + lane) * 16);
    bf16x8 vfA[8], vfB[8];
    const char* vp = vt_base + (size_t)(2 * kt) * SUB_B;
    #pragma unroll
    for (int ks = 0; ks < 2; ++ks)
      #pragma unroll
      for (int dt = 0; dt < 4; ++dt)
        vfA[ks * 4 + dt] = *(const bf16x8*)(vp + (dt * 128 + ks * 64 + lane) * 16);

    // ---- S^T = K Q (2 kv-subtiles) ----
    f32x16 st[2] = {};
    __builtin_amdgcn_s_setprio(1);
    #pragma unroll
    for (int t = 0; t < 2; ++t)
      #pragma unroll
      for (int s = 0; s < 8; ++s)
        st[t] = __builtin_amdgcn_mfma_f32_32x32x16_bf16(kf[t * 8 + s], qf[s], st[t], 0, 0, 0);
    __builtin_amdgcn_s_setprio(0);

    // ---- issue V second half; lands during softmax ----
    #pragma unroll
    for (int ks = 0; ks < 2; ++ks)
      #pragma unroll
      for (int dt = 0; dt < 4; ++dt)
        vfB[ks * 4 + dt] = *(const bf16x8*)(vp + SUB_B + (dt * 128 + ks * 64 + lane) * 16);

    // ---- causal mask (diagonal 64-tile only) ----
    if (kt == jt) {
      #pragma unroll
      for (int t = 0; t < 2; ++t)
        #pragma unroll
        for (int r = 0; r < 16; ++r) {
          int kv = 64 * kt + 32 * t + (r & 3) + 8 * (r >> 2) + 4 * hi;
          if (kv > qrow) st[t][r] = -1e30f;
        }
    }

    // ---- online softmax over 32 lane-local values ----
    float t16[8];
    #pragma unroll
    for (int e = 0; e < 8; ++e)
      t16[e] = fmaxf(fmaxf(st[0][e], st[0][e + 8]), fmaxf(st[1][e], st[1][e + 8]));
    float mx = fmaxf(fmaxf(fmaxf(t16[0], t16[1]), fmaxf(t16[2], t16[3])),
                     fmaxf(fmaxf(t16[4], t16[5]), fmaxf(t16[6], t16[7])));
    mx = xhalf_max(mx);
    // defer-max (T13, validated R8-R10)
    if (!__all(mx <= mrow + 8.0f)) {
      float mnew = fmaxf(mrow, mx);
      float alpha = exp2f(mrow - mnew);
      #pragma unroll
      for (int dt = 0; dt < 4; ++dt) o4[dt] *= alpha;
      lsum *= alpha;
      mrow = mnew;
    }
    #pragma unroll
    for (int t = 0; t < 2; ++t)
      #pragma unroll
      for (int e = 0; e < 16; ++e) st[t][e] = exp2f(st[t][e] - mrow);

    // ---- pack P^T (validated recipe, per kv-subtile) ----
    bf16x8 pb[4];
    #pragma unroll
    for (int t = 0; t < 2; ++t)
      #pragma unroll
      for (int cc = 0; cc < 2; ++cc) {
        const int r0 = cc * 8;
        uint32_t a0 = cvtpk(st[t][r0 + 0], st[t][r0 + 1]);
        uint32_t b0 = cvtpk(st[t][r0 + 4], st[t][r0 + 5]);
        asm volatile("v_permlane32_swap_b32 %0, %1" : "+v"(a0), "+v"(b0));
        uint32_t a1 = cvtpk(st[t][r0 + 2], st[t][r0 + 3]);
        uint32_t b1 = cvtpk(st[t][r0 + 6], st[t][r0 + 7]);
        asm volatile("v_permlane32_swap_b32 %0, %1" : "+v"(a1), "+v"(b1));
        union { uint32_t u[4]; bf16x8 v; } pu;
        pu.u[0] = a0; pu.u[1] = a1; pu.u[2] = b0; pu.u[3] = b1;
        pb[t * 2 + cc] = pu.v;
      }

    // ---- row-sum of P via ones-MFMA ----
    f32x16 pbsum = __builtin_amdgcn_mfma_f32_32x32x16_bf16(ones, pb[0], zero16, 0, 0, 0);
    pbsum = __builtin_amdgcn_mfma_f32_32x32x16_bf16(ones, pb[1], pbsum, 0, 0, 0);
    pbsum = __builtin_amdgcn_mfma_f32_32x32x16_bf16(ones, pb[2], pbsum, 0, 0, 0);
    pbsum = __builtin_amdgcn_mfma_f32_32x32x16_bf16(ones, pb[3], pbsum, 0, 0, 0);

    // ---- O^T += V^T P^T (4 k-slices of 16) ----
    __builtin_amdgcn_s_setprio(1);
    #pragma unroll
    for (int dt = 0; dt < 4; ++dt) {
      o4[dt] = __builtin_amdgcn_mfma_f32_32x32x16_bf16(vfA[0 * 4 + dt], pb[0], o4[dt], 0, 0, 0);
      o4[dt] = __builtin_amdgcn_mfma_f32_32x32x16_bf16(vfA[1 * 4 + dt], pb[1], o4[dt], 0, 0, 0);
      o4[dt] = __builtin_amdgcn_mfma_f32_32x32x16_bf16(vfB[0 * 4 + dt], pb[2], o4[dt], 0, 0, 0);
      o4[dt] = __builtin_amdgcn_mfma_f32_32x32x16_bf16(vfB[1 * 4 + dt], pb[3], o4[dt], 0, 0, 0);
    }
    __builtin_amdgcn_s_setprio(0);

    lsum += pbsum[0];
  }

  // ---- epilogue ----
  const float inv = 1.0f / lsum;
  float* op = O + ((size_t)h * S_LEN + qrow) * D_DIM;
  #pragma unroll
  for (int dt = 0; dt < 4; ++dt)
    #pragma unroll
    for (int rq = 0; rq < 4; ++rq) {
      f32x4 vv;
      #pragma unroll
      for (int jj = 0; jj < 4; ++jj) vv[jj] = o4[dt][rq * 4 + jj] * inv;
      *(f32x4*)(op + 32 * dt + 8 * rq + 4 * hi) = vv;
    }
}

extern "C" void kernel_launch(void* const* d_in, const int* in_sizes, int n_in,
                              void* d_out, int out_size, void* d_ws, size_t ws_size,
                              hipStream_t stream) {
  const float* Q = (const float*)d_in[0];
  const float* K = (const float*)d_in[1];
  const float* V = (const float*)d_in[2];
  float* O = (float*)d_out;
  ushort* wsK = (ushort*)d_ws;
  ushort* wsV = wsK + (size_t)8 * NT32 * (SUB_B / 2);   // +4MB
  prep_k<<<1024, 256, 0, stream>>>(K, wsK);
  prep_v<<<1024, 256, 0, stream>>>(V, wsV);
  attn_fwd<<<2048, 64, 0, stream>>>(Q, wsK, wsV, O);
}